// Round 12
// baseline (1108.623 us; speedup 1.0000x reference)
//
#include <hip/hip_runtime.h>
#include <hip/hip_bf16.h>
#include <cstdint>
#include <cstddef>

#define B_SZ   4
#define N_PTS  2048
#define KNN    20
#define BN_ROWS (B_SZ * N_PTS)
#define EPSV   1e-5f
#define SLOPEV 0.2f

typedef __attribute__((ext_vector_type(8))) short bf16x8;
typedef __attribute__((ext_vector_type(4))) float f32x4;

// ---------------------------------------------------------------- transpose + xx
__global__ void k_transpose(const float* __restrict__ x, float* __restrict__ xt,
                            float* __restrict__ xx)
{
    int i = blockIdx.x * 256 + threadIdx.x;
    if (i >= BN_ROWS) return;
    int b = i >> 11, n = i & 2047;
    float v0 = x[((b * 3 + 0) << 11) + n];
    float v1 = x[((b * 3 + 1) << 11) + n];
    float v2 = x[((b * 3 + 2) << 11) + n];
    xt[i * 3 + 0] = v0; xt[i * 3 + 1] = v1; xt[i * 3 + 2] = v2;
    xx[i] = fmaf(v0, v0, fmaf(v1, v1, v2 * v2));
}

// ---------------------------------------------------------------- batched weight prep
__global__ void k_prepw_all(const float* __restrict__ W1, const float* __restrict__ W2,
                            const float* __restrict__ W3, const float* __restrict__ W4,
                            const float* __restrict__ W5, const float* __restrict__ Wf,
                            float* __restrict__ wc, __hip_bfloat16* __restrict__ w5h,
                            float* __restrict__ wft)
{
    int i = blockIdx.x * 256 + threadIdx.x;
    if (i >= 876928) return;
    if (i >= 614784) {                      // Wf transpose
        int e = i - 614784;                 // e = o*1024 + f
        int o = e >> 10, f = e & 1023;
        wft[f * 256 + o] = Wf[e];
        return;
    }
    if (i >= 90496) {                       // W5 (1024x512) -> bf16
        int e = i - 90496;
        w5h[e] = __float2bfloat16(W5[e]);
        return;
    }
    const float* W; int O, C, off;
    if      (i < 384)   { W = W1; O = 64;  C = 3;   off = 0; }
    else if (i < 8576)  { W = W2; O = 64;  C = 64;  off = 384; }
    else if (i < 24960) { W = W3; O = 128; C = 64;  off = 8576; }
    else                { W = W4; O = 256; C = 128; off = 24960; }
    int e = i - off, j = e / C, c = e - j * C;
    float v;
    if (j < O) v = W[j * 2 * C + c];
    else { int jo = j - O; v = W[jo * 2 * C + C + c] - W[jo * 2 * C + c]; }
    wc[i] = v;
}

// ---------------------------------------------------------------- DIST GEMM (512-thread)
// r12: cross-k0 prefetch + LDS double-buffer, SPILL-PROOF codegen.
//  r2 failed: __launch_bounds__(256,2) capped VGPR->128 -> spill.
//  r10 failed: lambda-captured float4 prefetch regs -> addressable -> scratch
//              (FETCH 17->420MB, WRITE 65->874MB).
//  r12: NO lambdas. Prefetch values are 4 named float4s (no address taken);
//  load/store written inline via textual macro; per-thread global pointers +
//  one LDS offset hoisted (staging identity: row1=row0+64, kq1=kq0). Live set
//  ~40(base)+16(prefetch)+8(ptrs) ~= 64 VGPR.
//  One barrier per step: barrier ending step t-1 proves all waves done
//  reading buf[(t+1)&1] (== buf[(t-1)&1]). Staging layout + kk loop + FMA
//  order identical to r8 -> D2 bitwise identical.
//  SPILL TRIPWIRE: FETCH must stay ~17.3MB, WRITE 65.5MB.
template<bool VEC>
__launch_bounds__(512)
__global__ void k_dist(const float* __restrict__ A, int lda,
                       const float* __restrict__ xx,
                       float* __restrict__ C1, int Kd)
{
    constexpr int LDA_ = 132;              // 128 + 4 pad (k-major: [32 k][132])
    constexpr int LDT_ = 68;               // mirror T: [128 col][68]
    constexpr int BUFF = 32 * LDA_ * 2;    // As+Bs per buffer = 8448 floats
    __shared__ float smem[2 * BUFF];       // 67.6 KB (T needs 8704 <= BUFF+*)
    float* T  = smem;
    const int tid = threadIdx.x;
    const int tx  = tid & 31;              // 32 col groups x 4 cols = 128
    const int ty  = tid >> 5;              // 16 row groups

    int t = blockIdx.x;
    int it, jt;
    if (t < 120) {                          // off-diagonal pairs first
        int i = 0;
        for (; i < 15; ++i) { int cnt = 15 - i; if (t < cnt) break; t -= cnt; }
        it = i; jt = i + 1 + t;
    } else {                                // 16 diagonal tiles last (no mirror)
        it = jt = t - 120;
    }
    const int m0 = it * 128;
    const int n0 = jt * 128;
    const int b  = blockIdx.z;
    const float* Ab = A + (size_t)b * N_PTS * lda;

    float acc[2][4][4] = {};                // [ih(row half)][i(row)][c(col)]

    if constexpr (VEC) {
        const int nst  = Kd >> 5;           // Kd in {64,128} -> 2 or 4 steps
        const int row0 = tid >> 3, kq0 = tid & 7;
        // staging identity (r8): r=1 slice has row=row0+64, kq=kq0.
        const float* gA0 = Ab + (size_t)(m0 + row0) * lda + kq0 * 4;
        const float* gA1 = Ab + (size_t)(m0 + row0 + 64) * lda + kq0 * 4;
        const float* gB0 = Ab + (size_t)(n0 + row0) * lda + kq0 * 4;
        const float* gB1 = Ab + (size_t)(n0 + row0 + 64) * lda + kq0 * 4;
        const int s0 = (kq0 * 4) * LDA_ + row0;

        float4 pA0, pA1, pB0, pB1;

#define KD_STORE_TILE(BASEPTR) do {                                  \
        float* As_m = (BASEPTR);                                     \
        float* Bs_m = (BASEPTR) + 32 * LDA_;                         \
        As_m[s0 + 0 * LDA_]      = pA0.x;                            \
        As_m[s0 + 1 * LDA_]      = pA0.y;                            \
        As_m[s0 + 2 * LDA_]      = pA0.z;                            \
        As_m[s0 + 3 * LDA_]      = pA0.w;                            \
        As_m[s0 + 0 * LDA_ + 64] = pA1.x;                            \
        As_m[s0 + 1 * LDA_ + 64] = pA1.y;                            \
        As_m[s0 + 2 * LDA_ + 64] = pA1.z;                            \
        As_m[s0 + 3 * LDA_ + 64] = pA1.w;                            \
        Bs_m[s0 + 0 * LDA_]      = pB0.x;                            \
        Bs_m[s0 + 1 * LDA_]      = pB0.y;                            \
        Bs_m[s0 + 2 * LDA_]      = pB0.z;                            \
        Bs_m[s0 + 3 * LDA_]      = pB0.w;                            \
        Bs_m[s0 + 0 * LDA_ + 64] = pB1.x;                            \
        Bs_m[s0 + 1 * LDA_ + 64] = pB1.y;                            \
        Bs_m[s0 + 2 * LDA_ + 64] = pB1.z;                            \
        Bs_m[s0 + 3 * LDA_ + 64] = pB1.w;                            \
    } while (0)

        // prologue: stage step 0
        pA0 = *(const float4*)(gA0);
        pA1 = *(const float4*)(gA1);
        pB0 = *(const float4*)(gB0);
        pB1 = *(const float4*)(gB1);
        KD_STORE_TILE(smem);
        __syncthreads();

        for (int step = 0; step < nst; ++step) {
            float* As_ = smem + (step & 1) * BUFF;
            float* Bs_ = As_ + 32 * LDA_;
            const bool more = (step + 1 < nst);
            if (more) {                     // next tile's loads in flight
                const int ko = (step + 1) << 5;
                pA0 = *(const float4*)(gA0 + ko);
                pA1 = *(const float4*)(gA1 + ko);
                pB0 = *(const float4*)(gB0 + ko);
                pB1 = *(const float4*)(gB1 + ko);
            }

            // kk register double-buffer, full unroll (identical to r8)
            float4 ca0 = *(const float4*)&As_[ty * 4];
            float4 ca1 = *(const float4*)&As_[64 + ty * 4];
            float4 cb  = *(const float4*)&Bs_[tx * 4];
            #pragma unroll
            for (int kk = 0; kk < 32; ++kk) {
                float4 na0, na1, nb;
                if (kk < 31) {
                    na0 = *(const float4*)&As_[(kk + 1) * LDA_ + ty * 4];
                    na1 = *(const float4*)&As_[(kk + 1) * LDA_ + 64 + ty * 4];
                    nb  = *(const float4*)&Bs_[(kk + 1) * LDA_ + tx * 4];
                }
                float av[2][4] = {{ca0.x,ca0.y,ca0.z,ca0.w},{ca1.x,ca1.y,ca1.z,ca1.w}};
                float bw[4] = {cb.x, cb.y, cb.z, cb.w};
                #pragma unroll
                for (int ih = 0; ih < 2; ++ih)
                    #pragma unroll
                    for (int ii = 0; ii < 4; ++ii)
                        #pragma unroll
                        for (int jj = 0; jj < 4; ++jj)
                            acc[ih][ii][jj] = fmaf(av[ih][ii], bw[jj], acc[ih][ii][jj]);
                if (kk < 31) { ca0 = na0; ca1 = na1; cb = nb; }
            }
            if (more) KD_STORE_TILE(smem + ((step + 1) & 1) * BUFF);
            __syncthreads();
        }
#undef KD_STORE_TILE
    } else {
        // -------- legacy single-buffer path (L1, K=3: one partial step)
        float* As = smem;
        float* Bs = smem + 32 * LDA_;
        for (int k0 = 0; k0 < Kd; k0 += 32) {
            #pragma unroll
            for (int r = 0; r < 2; ++r) {
                int e = r * 512 + tid, row = e >> 3, kq = e & 7;
                #pragma unroll
                for (int j = 0; j < 4; ++j) {
                    int kg = k0 + kq * 4 + j;
                    As[(kq * 4 + j) * LDA_ + row] =
                        (kg < Kd) ? Ab[(size_t)(m0 + row) * lda + kg] : 0.f;
                }
            }
            #pragma unroll
            for (int r = 0; r < 2; ++r) {
                int e = r * 512 + tid, row = e >> 3, kq = e & 7;
                #pragma unroll
                for (int j = 0; j < 4; ++j) {
                    int kg = k0 + kq * 4 + j;
                    Bs[(kq * 4 + j) * LDA_ + row] =
                        (kg < Kd) ? Ab[(size_t)(n0 + row) * lda + kg] : 0.f;
                }
            }
            __syncthreads();

            int klen = Kd - k0; if (klen > 32) klen = 32;
            #pragma unroll 8
            for (int kk = 0; kk < klen; ++kk) {
                float4 a0 = *(const float4*)&As[kk * LDA_ + ty * 4];
                float4 a1 = *(const float4*)&As[kk * LDA_ + 64 + ty * 4];
                float4 bq = *(const float4*)&Bs[kk * LDA_ + tx * 4];
                float av[2][4] = {{a0.x,a0.y,a0.z,a0.w},{a1.x,a1.y,a1.z,a1.w}};
                float bw[4] = {bq.x, bq.y, bq.z, bq.w};
                #pragma unroll
                for (int ih = 0; ih < 2; ++ih)
                    #pragma unroll
                    for (int ii = 0; ii < 4; ++ii)
                        #pragma unroll
                        for (int jj = 0; jj < 4; ++jj)
                            acc[ih][ii][jj] = fmaf(av[ih][ii], bw[jj], acc[ih][ii][jj]);
            }
            __syncthreads();
        }
    }

    const float* xxb = xx + b * N_PTS;
    float xj[4];
    {
        float4 v = *(const float4*)&xxb[n0 + tx * 4];
        xj[0] = v.x; xj[1] = v.y; xj[2] = v.z; xj[3] = v.w;
    }
    float xiv[2][4];
    #pragma unroll
    for (int ih = 0; ih < 2; ++ih)
        #pragma unroll
        for (int i = 0; i < 4; ++i)
            xiv[ih][i] = xxb[m0 + ih * 64 + ty * 4 + i];
    const bool diag = (m0 == n0);
    const size_t zoff = (size_t)b * N_PTS;

    #pragma unroll
    for (int ih = 0; ih < 2; ++ih)
        #pragma unroll
        for (int i = 0; i < 4; ++i) {
            int gi = m0 + ih * 64 + ty * 4 + i;
            float xi = xiv[ih][i];
            int gj = n0 + tx * 4;
            float4 v;
            v.x = 2.f * acc[ih][i][0] - xi - xj[0];
            v.y = 2.f * acc[ih][i][1] - xi - xj[1];
            v.z = 2.f * acc[ih][i][2] - xi - xj[2];
            v.w = 2.f * acc[ih][i][3] - xi - xj[3];
            if (diag) {
                if (gi == gj + 0) v.x = 0.f;
                if (gi == gj + 1) v.y = 0.f;
                if (gi == gj + 2) v.z = 0.f;
                if (gi == gj + 3) v.w = 0.f;
            }
            *(float4*)&C1[(zoff + gi) * N_PTS + gj] = v;
        }

    if (!diag) {                            // mirror: D2[j][i], LDS transpose
        #pragma unroll
        for (int ih = 0; ih < 2; ++ih) {
            #pragma unroll
            for (int c = 0; c < 4; ++c) {
                float xjc = xj[c];
                float4 tv;
                tv.x = 2.f * acc[ih][0][c] - xjc - xiv[ih][0];
                tv.y = 2.f * acc[ih][1][c] - xjc - xiv[ih][1];
                tv.z = 2.f * acc[ih][2][c] - xjc - xiv[ih][2];
                tv.w = 2.f * acc[ih][3][c] - xjc - xiv[ih][3];
                *(float4*)&T[(tx * 4 + c) * LDT_ + ty * 4] = tv;
            }
            __syncthreads();
            #pragma unroll
            for (int r = 0; r < 4; ++r) {
                int e = r * 512 + tid;
                int jr = e >> 4, c4 = e & 15;
                float4 tv = *(const float4*)&T[jr * LDT_ + c4 * 4];
                *(float4*)&C1[(zoff + n0 + jr) * N_PTS + m0 + ih * 64 + c4 * 4] = tv;
            }
            __syncthreads();
        }
    }
}

// ---------------------------------------------------------------- bf16 MFMA GEMM (layer 5)
__launch_bounds__(256)
__global__ void k_gemm5(const unsigned short* __restrict__ Ah,
                        const unsigned short* __restrict__ Bh,
                        float* __restrict__ Cf,
                        float* __restrict__ ssum, float* __restrict__ ssumsq)
{
    constexpr int LDA = 72;
    __shared__ unsigned short As[128 * LDA];
    __shared__ unsigned short Bs[128 * LDA];
    const int tid  = threadIdx.x;
    const int lane = tid & 63;
    const int w    = tid >> 6;
    const int wr   = w >> 1, wcl = w & 1;
    const int quad = lane >> 4;
    const int l16  = lane & 15;
    const int m0 = blockIdx.y * 128;
    const int n0 = blockIdx.x * 128;

    f32x4 acc[4][4] = {};

    for (int k0 = 0; k0 < 512; k0 += 64) {
        #pragma unroll
        for (int r = 0; r < 4; ++r) {
            int e = r * 256 + tid, row = e >> 3, kq = e & 7;
            *(uint4*)&As[row * LDA + kq * 8] =
                *(const uint4*)&Ah[(size_t)(m0 + row) * 512 + k0 + kq * 8];
        }
        #pragma unroll
        for (int r = 0; r < 4; ++r) {
            int e = r * 256 + tid, row = e >> 3, kq = e & 7;
            *(uint4*)&Bs[row * LDA + kq * 8] =
                *(const uint4*)&Bh[(size_t)(n0 + row) * 512 + k0 + kq * 8];
        }
        __syncthreads();
        #pragma unroll
        for (int kk = 0; kk < 64; kk += 32) {
            bf16x8 af[4], bfr[4];
            #pragma unroll
            for (int i = 0; i < 4; ++i)
                af[i] = *(const bf16x8*)&As[(wr * 64 + i * 16 + l16) * LDA + kk + quad * 8];
            #pragma unroll
            for (int j = 0; j < 4; ++j)
                bfr[j] = *(const bf16x8*)&Bs[(wcl * 64 + j * 16 + l16) * LDA + kk + quad * 8];
            #pragma unroll
            for (int i = 0; i < 4; ++i)
                #pragma unroll
                for (int j = 0; j < 4; ++j)
                    acc[i][j] = __builtin_amdgcn_mfma_f32_16x16x32_bf16(af[i], bfr[j], acc[i][j], 0, 0, 0);
        }
        __syncthreads();
    }

    #pragma unroll
    for (int i = 0; i < 4; ++i) {
        int rbase = m0 + wr * 64 + i * 16 + quad * 4;
        #pragma unroll
        for (int j = 0; j < 4; ++j) {
            int col = n0 + wcl * 64 + j * 16 + l16;
            #pragma unroll
            for (int r = 0; r < 4; ++r)
                Cf[(size_t)(rbase + r) * 1024 + col] = acc[i][j][r];
        }
    }

    float* sredS = (float*)As;
    float* sredQ = (float*)Bs;
    #pragma unroll
    for (int j = 0; j < 4; ++j) {
        float s = 0.f, q = 0.f;
        #pragma unroll
        for (int i = 0; i < 4; ++i)
            #pragma unroll
            for (int r = 0; r < 4; ++r) {
                float v = acc[i][j][r];
                s += v; q = fmaf(v, v, q);
            }
        int coll = wcl * 64 + j * 16 + l16;
        int slot = wr * 4 + quad;
        sredS[coll * 8 + slot] = s;
        sredQ[coll * 8 + slot] = q;
    }
    __syncthreads();
    if (tid < 128) {
        float s = 0.f, q = 0.f;
        #pragma unroll
        for (int t = 0; t < 8; ++t) { s += sredS[tid * 8 + t]; q += sredQ[tid * 8 + t]; }
        ssum  [blockIdx.y * 1024 + n0 + tid] = s;
        ssumsq[blockIdx.y * 1024 + n0 + tid] = q;
    }
}

// ---------------------------------------------------------------- FUSED select + GD GEMM
// GD part: unchanged (r6). Select: r9 form (lane-max 20th-largest lower bound
// at 1 ballot/iter + 4-candidate main bisection; exact full-count fallback).
template<bool VEC>
__launch_bounds__(256)
__global__ void k_selgd(const float* __restrict__ D2, int* __restrict__ idx_out,
                        const float* __restrict__ A, int lda,
                        const float* __restrict__ Bm, int ldb,
                        float* __restrict__ C1, float* __restrict__ C2,
                        int Nn, int Kd, int gdBlocks, int gdsh)
{
    constexpr int LDA_ = 132;
    constexpr int LDB_ = 68;
    __shared__ float smem[32 * LDA_ + 32 * LDB_];   // 25.6 KB (GD path only)

    if ((int)blockIdx.x < gdBlocks) {
        // ================= GD GEMM path =================
        float* As = smem;
        float* Bs = smem + 32 * LDA_;
        const int tid = threadIdx.x;
        const int tx  = tid & 15;
        const int ty  = tid >> 4;
        const int gdx = Nn >> 6;
        const int bx  = blockIdx.x & (gdx - 1);
        const int by  = blockIdx.x >> gdsh;
        const int m0 = by * 128;
        const int n0 = bx * 64;

        float acc[2][4][4] = {};

        for (int k0 = 0; k0 < Kd; k0 += 32) {
            #pragma unroll
            for (int r = 0; r < 4; ++r) {            // A: 128 rows x 32 k
                int e = r * 256 + tid, row = e >> 3, kq = e & 7;
                if constexpr (VEC) {
                    float4 v = *(const float4*)&A[(size_t)(m0 + row) * lda + k0 + kq * 4];
                    As[(kq * 4 + 0) * LDA_ + row] = v.x;
                    As[(kq * 4 + 1) * LDA_ + row] = v.y;
                    As[(kq * 4 + 2) * LDA_ + row] = v.z;
                    As[(kq * 4 + 3) * LDA_ + row] = v.w;
                } else {
                    #pragma unroll
                    for (int j = 0; j < 4; ++j) {
                        int kg = k0 + kq * 4 + j;
                        As[(kq * 4 + j) * LDA_ + row] =
                            (kg < Kd) ? A[(size_t)(m0 + row) * lda + kg] : 0.f;
                    }
                }
            }
            #pragma unroll
            for (int r = 0; r < 2; ++r) {            // B: 64 rows x 32 k
                int e = r * 256 + tid, row = e >> 3, kq = e & 7;
                if constexpr (VEC) {
                    float4 v = *(const float4*)&Bm[(size_t)(n0 + row) * ldb + k0 + kq * 4];
                    Bs[(kq * 4 + 0) * LDB_ + row] = v.x;
                    Bs[(kq * 4 + 1) * LDB_ + row] = v.y;
                    Bs[(kq * 4 + 2) * LDB_ + row] = v.z;
                    Bs[(kq * 4 + 3) * LDB_ + row] = v.w;
                } else {
                    #pragma unroll
                    for (int j = 0; j < 4; ++j) {
                        int kg = k0 + kq * 4 + j;
                        Bs[(kq * 4 + j) * LDB_ + row] =
                            (kg < Kd) ? Bm[(size_t)(n0 + row) * ldb + kg] : 0.f;
                    }
                }
            }
            __syncthreads();

            if constexpr (VEC) {
                float4 ca0 = *(const float4*)&As[ty * 4];
                float4 ca1 = *(const float4*)&As[64 + ty * 4];
                float4 cb0 = *(const float4*)&Bs[tx * 4];
                #pragma unroll
                for (int kk = 0; kk < 32; ++kk) {
                    float4 na0, na1, nb0;
                    if (kk < 31) {
                        na0 = *(const float4*)&As[(kk + 1) * LDA_ + ty * 4];
                        na1 = *(const float4*)&As[(kk + 1) * LDA_ + 64 + ty * 4];
                        nb0 = *(const float4*)&Bs[(kk + 1) * LDB_ + tx * 4];
                    }
                    float av[2][4] = {{ca0.x,ca0.y,ca0.z,ca0.w},{ca1.x,ca1.y,ca1.z,ca1.w}};
                    float bw[4] = {cb0.x, cb0.y, cb0.z, cb0.w};
                    #pragma unroll
                    for (int ih = 0; ih < 2; ++ih)
                        #pragma unroll
                        for (int ii = 0; ii < 4; ++ii)
                            #pragma unroll
                            for (int jj = 0; jj < 4; ++jj)
                                acc[ih][ii][jj] = fmaf(av[ih][ii], bw[jj], acc[ih][ii][jj]);
                    if (kk < 31) { ca0 = na0; ca1 = na1; cb0 = nb0; }
                }
            } else {
                int klen = Kd - k0; if (klen > 32) klen = 32;
                #pragma unroll 8
                for (int kk = 0; kk < klen; ++kk) {
                    float4 a0 = *(const float4*)&As[kk * LDA_ + ty * 4];
                    float4 a1 = *(const float4*)&As[kk * LDA_ + 64 + ty * 4];
                    float4 bq = *(const float4*)&Bs[kk * LDB_ + tx * 4];
                    float av[2][4] = {{a0.x,a0.y,a0.z,a0.w},{a1.x,a1.y,a1.z,a1.w}};
                    float bw[4] = {bq.x, bq.y, bq.z, bq.w};
                    #pragma unroll
                    for (int ih = 0; ih < 2; ++ih)
                        #pragma unroll
                        for (int ii = 0; ii < 4; ++ii)
                            #pragma unroll
                            for (int jj = 0; jj < 4; ++jj)
                                acc[ih][ii][jj] = fmaf(av[ih][ii], bw[jj], acc[ih][ii][jj]);
                }
            }
            __syncthreads();
        }

        const int Oo = Nn >> 1;
        #pragma unroll
        for (int ih = 0; ih < 2; ++ih)
            #pragma unroll
            for (int i = 0; i < 4; ++i) {
                int row = m0 + ih * 64 + ty * 4 + i;
                int colg = n0 + tx * 4;
                float4 v = make_float4(acc[ih][i][0], acc[ih][i][1],
                                       acc[ih][i][2], acc[ih][i][3]);
                if (colg < Oo) *(float4*)&C1[(size_t)row * Oo + colg] = v;
                else           *(float4*)&C2[(size_t)row * Oo + colg - Oo] = v;
            }
        return;
    }

    // ================= select path =================
    const int lane = threadIdx.x & 63;
    const int w    = threadIdx.x >> 6;
    const int qloc = ((int)blockIdx.x - gdBlocks) * 4 + w;   // 0..8191
    const float* row = D2 + (size_t)qloc * N_PTS;

    unsigned key[32];
    #pragma unroll
    for (int c = 0; c < 8; ++c) {
        float4 v = *(const float4*)&row[c * 256 + lane * 4];
        float vv[4] = {v.x, v.y, v.z, v.w};
        #pragma unroll
        for (int r = 0; r < 4; ++r) {
            unsigned u = __float_as_uint(vv[r]);
            key[c * 4 + r] = ((int)u >= 0) ? (u | 0x80000000u) : ~u;
        }
    }

    // per-lane max + wave min/max of lane maxes
    unsigned lmax = 0u;
    #pragma unroll
    for (int e = 0; e < 32; ++e) lmax = (key[e] > lmax) ? key[e] : lmax;
    unsigned gmin = lmax, gmax = lmax;
    #pragma unroll
    for (int s = 32; s >= 1; s >>= 1) {
        unsigned o1 = __shfl_xor(gmin, s, 64);
        unsigned o2 = __shfl_xor(gmax, s, 64);
        gmin = (o1 < gmin) ? o1 : gmin;
        gmax = (o2 > gmax) ? o2 : gmax;
    }

    // lo = exact 20th-largest lane-max via 1-ballot-per-iter bisection
    unsigned lo = gmin, hi2 = gmax;
    while (lo < hi2) {
        unsigned mid = lo + ((hi2 - lo) >> 1);
        int c = __popcll(__ballot(lmax > mid));
        if (c < KNN) hi2 = mid; else lo = mid + 1;
    }
    unsigned hi = gmax;

    // candidates >= lo (cap 4/lane; fake 0s never counted since mid >= lo > 0)
    unsigned c0 = 0u, c1 = 0u, c2 = 0u, c3 = 0u;
    int nc = 0;
    #pragma unroll
    for (int e = 0; e < 32; ++e) {
        unsigned k = key[e];
        if (k >= lo) {
            if (nc == 0) c0 = k; else if (nc == 1) c1 = k;
            else if (nc == 2) c2 = k; else if (nc == 3) c3 = k;
            ++nc;
        }
    }
    if (__ballot(nc > 4)) {
        // rare overflow: exact full-count bisection from current bounds
        while (lo < hi) {
            unsigned mid = lo + ((hi - lo) >> 1);
            int cnt = 0;
            #pragma unroll
            for (int e = 0; e < 32; ++e)
                cnt += __popcll(__ballot(key[e] > mid));
            if (cnt < KNN) hi = mid; else lo = mid + 1;
        }
    } else {
        // main bisection: 4 ballots/iter (cnt == count(key > mid) exactly)
        while (lo < hi) {
            unsigned mid = lo + ((hi - lo) >> 1);
            int cnt = __popcll(__ballot(c0 > mid))
                    + __popcll(__ballot(c1 > mid))
                    + __popcll(__ballot(c2 > mid))
                    + __popcll(__ballot(c3 > mid));
            if (cnt < KNN) hi = mid; else lo = mid + 1;
        }
    }
    const unsigned T = lo;

    int* outp = idx_out + (size_t)qloc * KNN;
    const unsigned long long ltmask = (lane == 0) ? 0ull : (~0ull >> (64 - lane));
    int base = 0;
    #pragma unroll
    for (int e = 0; e < 32; ++e) {
        bool p = key[e] > T;
        unsigned long long m = __ballot(p);
        if (p) {
            int pos = base + __popcll(m & ltmask);
            outp[pos] = (e >> 2) * 256 + lane * 4 + (e & 3);
        }
        base += __popcll(m);
    }
    // tie-fill: fully unrolled (no dynamic trip count!), writes guarded by pos<KNN
    #pragma unroll
    for (int e = 0; e < 32; ++e) {
        bool p = key[e] == T;
        unsigned long long m = __ballot(p);
        if (p) {
            int pos = base + __popcll(m & ltmask);
            if (pos < KNN) outp[pos] = (e >> 2) * 256 + lane * 4 + (e & 3);
        }
        base += __popcll(m);
    }
}

// ---------------------------------------------------------------- gather + stats
// sign(sc) == sign(gamma) (rsqrtf > 0), so max-vs-min selection is known up
// front; write ONE hsel array (r9).
template<int O, int NSEQ>
__launch_bounds__(256)
__global__ void k_gather(const float* __restrict__ gtab, const float* __restrict__ dtab,
                         const int* __restrict__ idx, const float* __restrict__ gamma,
                         float* __restrict__ hsel,
                         float* __restrict__ ssum, float* __restrict__ ssumsq)
{
    constexpr int NPB = 256 / O;
    const int grp = threadIdx.x / O;
    const int o   = threadIdx.x & (O - 1);
    const float g = gamma[o];
    float accS = 0.f, accS2 = 0.f;
    const int rowsPerBlock = NPB * NSEQ;
    const int batch = blockIdx.x & 3;
    const int chunk = blockIdx.x >> 2;
    const int bbase = batch << 11;
    for (int s = 0; s < NSEQ; ++s) {
        int row = bbase + chunk * rowsPerBlock + s * NPB + grp;
        const int* ip = idx + (size_t)row * KNN;
        float gmax = -INFINITY, gmin = INFINITY, gs = 0.f, gs2 = 0.f;
        for (int k = 0; k < KNN; ++k) {
            int nb = ip[k];
            float v = gtab[(size_t)(bbase + nb) * O + o];
            gmax = fmaxf(gmax, v);
            gmin = fminf(gmin, v);
            gs  += v;
            gs2  = fmaf(v, v, gs2);
        }
        float d = dtab[(size_t)row * O + o];
        float keep = (g >= 0.f) ? gmax : gmin;
        hsel[(size_t)row * O + o] = keep + d;
        accS  += gs + (float)KNN * d;
        accS2 += gs2 + 2.f * d * gs + (float)KNN * d * d;
    }
    int bank = blockIdx.x & 63;
    atomicAdd(&ssum[bank * O + o], accS);
    atomicAdd(&ssumsq[bank * O + o], accS2);
}

// ---------------------------------------------------------------- normalize (+BN finalize, +xx, +bf16 mirror)
template<int O, bool WRITE_XX>
__launch_bounds__(256)
__global__ void k_normalize(const float* __restrict__ hsel,
                            const float* __restrict__ ssum, const float* __restrict__ ssumsq,
                            const float* __restrict__ gamma, const float* __restrict__ beta,
                            float invM, float* __restrict__ xcs,
                            __hip_bfloat16* __restrict__ xch, float* __restrict__ xx)
{
    const int tid = threadIdx.x;
    const int o   = tid & (O - 1);
    float s = 0.f, s2 = 0.f;
    #pragma unroll 8
    for (int bk = 0; bk < 64; ++bk) { s += ssum[bk * O + o]; s2 += ssumsq[bk * O + o]; }
    float mean = s * invM;
    float var  = fmaf(-mean, mean, s2 * invM);
    float sc   = gamma[o] * rsqrtf(var + EPSV);
    float sh   = beta[o] - mean * sc;

    constexpr int R = 256 / O;
    const int rloc = tid / O;
    __shared__ float part[4];
    const int ngroups = BN_ROWS / R;
    for (int gidx = blockIdx.x; gidx < ngroups; gidx += gridDim.x) {
        int row = gidx * R + rloc;
        size_t i = (size_t)row * O + o;
        float h = hsel[i];                      // pre-selected by sign(gamma)
        float y = fmaf(h, sc, sh);
        y = (y >= 0.f) ? y : SLOPEV * y;
        xcs[(size_t)row * 512 + o] = y;
        xch[(size_t)row * 512 + o] = __float2bfloat16(y);
        if constexpr (WRITE_XX) {
            float p = y * y;
            #pragma unroll
            for (int sft = 32; sft >= 1; sft >>= 1) p += __shfl_xor(p, sft, 64);
            if constexpr (O == 64) {
                if ((tid & 63) == 0) xx[row] = p;
            } else {
                if ((tid & 63) == 0) part[tid >> 6] = p;
                __syncthreads();
                if constexpr (O == 128) {
                    if (tid < 2) xx[gidx * R + tid] = part[2 * tid] + part[2 * tid + 1];
                } else {
                    if (tid == 0) xx[gidx * R] = (part[0] + part[1]) + (part[2] + part[3]);
                }
                __syncthreads();
            }
        }
    }
}

// ---------------------------------------------------------------- seg max/sum (+finalize, 64 banks)
__global__ void k_seg(const float* __restrict__ h,
                      const float* __restrict__ ssum, const float* __restrict__ ssumsq,
                      const float* __restrict__ gamma, const float* __restrict__ beta,
                      float* __restrict__ smax, float* __restrict__ ssumseg)
{
    int f = blockIdx.y * 256 + threadIdx.x;
    float s = 0.f, s2 = 0.f;
    #pragma unroll 8
    for (int bk = 0; bk < 64; ++bk) { s += ssum[bk * 1024 + f]; s2 += ssumsq[bk * 1024 + f]; }
    const float invM = 1.f / (float)BN_ROWS;
    float mean = s * invM;
    float var  = fmaf(-mean, mean, s2 * invM);
    float sc   = gamma[f] * rsqrtf(var + EPSV);
    float sh   = beta[f] - mean * sc;

    int seg = blockIdx.x;
    float mx = -INFINITY, sm = 0.f;
    int n0 = seg * 64;
    for (int i = 0; i < 64; ++i) {
        float v = fmaf(h[(size_t)(n0 + i) * 1024 + f], sc, sh);
        v = (v >= 0.f) ? v : SLOPEV * v;
        mx = fmaxf(mx, v); sm += v;
    }
    smax[(size_t)seg * 1024 + f]    = mx;
    ssumseg[(size_t)seg * 1024 + f] = sm;
}

// ---------------------------------------------------------------- final projection (+bin combine)
__launch_bounds__(256)
__global__ void k_final(const float* __restrict__ smax, const float* __restrict__ ssg,
                        const float* __restrict__ Wft, const float* __restrict__ bfeat,
                        float* __restrict__ out)
{
    __shared__ float row[1024];
    __shared__ float part[1024];
    const int tid = threadIdx.x;
    int sb = blockIdx.x;             // s*4 + b, s in 0..62
    int s = sb >> 2, b = sb & 3;
    int nb = (s == 0) ? 1 : (s < 3) ? 2 : (s < 7) ? 4 : (s < 15) ? 8 : (s < 31) ? 16 : 32;
    int idxL = s - (nb - 1);
    int segc = 32 / nb;
    int seg0 = b * 32 + idxL * segc;
    float inv = 1.f / (float)(64 * segc);
    for (int c = tid; c < 1024; c += 256) {
        float mx = -INFINITY, sm = 0.f;
        for (int t = 0; t < segc; ++t) {
            mx = fmaxf(mx, smax[(size_t)(seg0 + t) * 1024 + c]);
            sm += ssg[(size_t)(seg0 + t) * 1024 + c];
        }
        row[c] = mx + sm * inv;
    }
    __syncthreads();

    const int lane = tid & 63;
    const int w    = tid >> 6;
    const float* rw = row + w * 256;
    const float* wp = Wft + (size_t)(w * 256) * 256 + lane * 4;
    float4 a0 = {0,0,0,0}, a1 = {0,0,0,0}, a2 = {0,0,0,0}, a3 = {0,0,0,0};
    for (int f = 0; f < 256; f += 4) {
        float r0 = rw[f + 0], r1 = rw[f + 1], r2 = rw[f + 2], r3 = rw[f + 3];
        float4 w0 = *(const float4*)&wp[(size_t)(f + 0) * 256];
        float4 w1 = *(const float4*)&wp[(size_t)(f + 1) * 256];
        float4 w2 = *(const float4*)&wp[(size_t)(f + 2) * 256];
        float4 w3 = *(const float4*)&wp[(size_t)(f + 3) * 256];
        a0.x = fmaf(r0, w0.x, a0.x); a0.y = fmaf(r0, w0.y, a0.y);
        a0.z = fmaf(r0, w0.z, a0.z); a0.w = fmaf(r0, w0.w, a0.w);
        a1.x = fmaf(r1, w1.x, a1.x); a1.y = fmaf(r1, w1.y, a1.y);
        a1.z = fmaf(r1, w1.z, a1.z); a1.w = fmaf(r1, w1.w, a1.w);
        a2.x = fmaf(r2, w2.x, a2.x); a2.y = fmaf(r2, w2.y, a2.y);
        a2.z = fmaf(r2, w2.z, a2.z); a2.w = fmaf(r2, w2.w, a2.w);
        a3.x = fmaf(r3, w3.x, a3.x); a3.y = fmaf(r3, w3.y, a3.y);
        a3.z = fmaf(r3, w3.z, a3.z); a3.w = fmaf(r3, w3.w, a3.w);
    }
    float4 a;
    a.x = (a0.x + a1.x) + (a2.x + a3.x);
    a.y = (a0.y + a1.y) + (a2.y + a3.y);
    a.z = (a0.z + a1.z) + (a2.z + a3.z);
    a.w = (a0.w + a1.w) + (a2.w + a3.w);
    *(float4*)&part[w * 256 + lane * 4] = a;
    __syncthreads();
    int o = tid;
    float acc = (part[o] + part[256 + o]) + (part[512 + o] + part[768 + o]);
    out[(size_t)sb * 256 + o] = acc + bfeat[o];
}

// ================================================================ launch
extern "C" void kernel_launch(void* const* d_in, const int* in_sizes, int n_in,
                              void* d_out, int out_size, void* d_ws, size_t ws_size,
                              hipStream_t stream)
{
    const float* x  = (const float*)d_in[0];
    const float* W1 = (const float*)d_in[1];
    const float* g1 = (const float*)d_in[2];
    const float* b1 = (const float*)d_in[3];
    const float* W2 = (const float*)d_in[4];
    const float* g2 = (const float*)d_in[5];
    const float* b2 = (const float*)d_in[6];
    const float* W3 = (const float*)d_in[7];
    const float* g3 = (const float*)d_in[8];
    const float* b3 = (const float*)d_in[9];
    const float* W4 = (const float*)d_in[10];
    const float* g4 = (const float*)d_in[11];
    const float* b4 = (const float*)d_in[12];
    const float* W5 = (const float*)d_in[13];
    const float* g5 = (const float*)d_in[14];
    const float* b5 = (const float*)d_in[15];
    const float* Wf = (const float*)d_in[16];
    const float* bfeat = (const float*)d_in[17];
    float* out = (float*)d_out;
    float* ws  = (float*)d_ws;

    // workspace layout (floats), total 32,727,552 = 130.9 MB (ws_size ~268 MB)
    float* xt1   = ws + 0;            // 24576
    int*   idx   = (int*)(ws + 24576);// 163840
    float* xx    = ws + 188416;       // 8192
    float* xc    = ws + 196608;       // 8192*512
    float* hsel  = ws + 4390912;      // 8192*256
    float* stats = ws + 8585216;      // 65536 (L1@0 L2@8192 L3@16384 L4@32768)
    float* smax  = ws + 8650752;      // 128*1024
    float* ssg   = ws + 8781824;      // 128*1024
    float* wc    = ws + 8912896;      // 90624
    float* big   = ws + 9003520;      // 16,777,216 (4-batch D2 | h5)
    __hip_bfloat16* xch = (__hip_bfloat16*)(ws + 25780736);  // 8192*512 bf16
    __hip_bfloat16* w5h = (__hip_bfloat16*)(ws + 27877888);  // 1024*512 bf16
    float* wft   = ws + 28140032;     // 1024*256 transposed Wf
    float* l5s   = ws + 28402176;     // 64*1024 L5 col sums
    float* l5q   = ws + 28467712;     // 64*1024 L5 col sumsq
    float* gtab  = ws + 28533248;     // 8192*256 (outside big: selgd overlap)
    float* dtab  = ws + 30630400;     // 8192*256  (end: 32,727,552)

    hipMemsetAsync(stats, 0, 65536 * sizeof(float), stream);
    k_transpose<<<32, 256, 0, stream>>>(x, xt1, xx);
    k_prepw_all<<<3426, 256, 0, stream>>>(W1, W2, W3, W4, W5, Wf, wc, w5h, wft);

    const float invMk = 1.f / (float)(BN_ROWS * KNN);

    // ------------- layer 1: C=3, O=64
    {
        float* ss = stats + 0;
        k_dist<false><<<dim3(136, 1, 4), 512, 0, stream>>>(xt1, 3, xx, big, 3);
        k_selgd<false><<<128 + 2048, 256, 0, stream>>>(big, idx, xt1, 3, wc, 3, gtab, dtab, 128, 3, 128, 1);
        k_gather<64, 8><<<256, 256, 0, stream>>>(gtab, dtab, idx, g1, hsel, ss, ss + 4096);
        k_normalize<64, true><<<512, 256, 0, stream>>>(hsel, ss, ss + 4096, g1, b1, invMk, xc + 0, xch + 0, xx);
    }
    // ------------- layer 2: C=64, O=64
    {
        float* ss = stats + 8192;
        k_dist<true><<<dim3(136, 1, 4), 512, 0, stream>>>(xc + 0, 512, xx, big, 64);
        k_selgd<true><<<128 + 2048, 256, 0, stream>>>(big, idx, xc + 0, 512, wc + 384, 64, gtab, dtab, 128, 64, 128, 1);
        k_gather<64, 8><<<256, 256, 0, stream>>>(gtab, dtab, idx, g2, hsel, ss, ss + 4096);
        k_normalize<64, true><<<512, 256, 0, stream>>>(hsel, ss, ss + 4096, g2, b2, invMk, xc + 64, xch + 64, xx);
    }
    // ------------- layer 3: C=64, O=128
    {
        float* ss = stats + 16384;
        k_dist<true><<<dim3(136, 1, 4), 512, 0, stream>>>(xc + 64, 512, xx, big, 64);
        k_selgd<true><<<256 + 2048, 256, 0, stream>>>(big, idx, xc + 64, 512, wc + 8576, 64, gtab, dtab, 256, 64, 256, 2);
        k_gather<128, 8><<<512, 256, 0, stream>>>(gtab, dtab, idx, g3, hsel, ss, ss + 8192);
        k_normalize<128, true><<<512, 256, 0, stream>>>(hsel, ss, ss + 8192, g3, b3, invMk, xc + 128, xch + 128, xx);
    }
    // ------------- layer 4: C=128, O=256
    {
        float* ss = stats + 32768;
        k_dist<true><<<dim3(136, 1, 4), 512, 0, stream>>>(xc + 128, 512, xx, big, 128);
        k_selgd<true><<<512 + 2048, 256, 0, stream>>>(big, idx, xc + 128, 512, wc + 24960, 128, gtab, dtab, 512, 128, 512, 3);
        k_gather<256, 8><<<1024, 256, 0, stream>>>(gtab, dtab, idx, g4, hsel, ss, ss + 16384);
        k_normalize<256, false><<<512, 256, 0, stream>>>(hsel, ss, ss + 16384, g4, b4, invMk, xc + 256, xch + 256, xx);
    }
    // ------------- layer 5: bf16 MFMA GEMM (+fused stats), seg, final
    {
        k_gemm5<<<dim3(8, 64), 256, 0, stream>>>((const unsigned short*)xch, (const unsigned short*)w5h, big, l5s, l5q);
        k_seg<<<dim3(128, 4), 256, 0, stream>>>(big, l5s, l5q, g5, b5, smax, ssg);
        k_final<<<252, 256, 0, stream>>>(smax, ssg, wft, bfeat, out);
    }
}

// Round 13
// 482.703 us; speedup vs baseline: 2.2967x; 2.2967x over previous
//
#include <hip/hip_runtime.h>
#include <hip/hip_bf16.h>
#include <cstdint>
#include <cstddef>

#define B_SZ   4
#define N_PTS  2048
#define KNN    20
#define BN_ROWS (B_SZ * N_PTS)
#define EPSV   1e-5f
#define SLOPEV 0.2f

typedef __attribute__((ext_vector_type(8))) short bf16x8;
typedef __attribute__((ext_vector_type(4))) float f32x4;

// ---------------------------------------------------------------- transpose + xx
__global__ void k_transpose(const float* __restrict__ x, float* __restrict__ xt,
                            float* __restrict__ xx)
{
    int i = blockIdx.x * 256 + threadIdx.x;
    if (i >= BN_ROWS) return;
    int b = i >> 11, n = i & 2047;
    float v0 = x[((b * 3 + 0) << 11) + n];
    float v1 = x[((b * 3 + 1) << 11) + n];
    float v2 = x[((b * 3 + 2) << 11) + n];
    xt[i * 3 + 0] = v0; xt[i * 3 + 1] = v1; xt[i * 3 + 2] = v2;
    xx[i] = fmaf(v0, v0, fmaf(v1, v1, v2 * v2));
}

// ---------------------------------------------------------------- batched weight prep
__global__ void k_prepw_all(const float* __restrict__ W1, const float* __restrict__ W2,
                            const float* __restrict__ W3, const float* __restrict__ W4,
                            const float* __restrict__ W5, const float* __restrict__ Wf,
                            float* __restrict__ wc, __hip_bfloat16* __restrict__ w5h,
                            float* __restrict__ wft)
{
    int i = blockIdx.x * 256 + threadIdx.x;
    if (i >= 876928) return;
    if (i >= 614784) {                      // Wf transpose
        int e = i - 614784;                 // e = o*1024 + f
        int o = e >> 10, f = e & 1023;
        wft[f * 256 + o] = Wf[e];
        return;
    }
    if (i >= 90496) {                       // W5 (1024x512) -> bf16
        int e = i - 90496;
        w5h[e] = __float2bfloat16(W5[e]);
        return;
    }
    const float* W; int O, C, off;
    if      (i < 384)   { W = W1; O = 64;  C = 3;   off = 0; }
    else if (i < 8576)  { W = W2; O = 64;  C = 64;  off = 384; }
    else if (i < 24960) { W = W3; O = 128; C = 64;  off = 8576; }
    else                { W = W4; O = 256; C = 128; off = 24960; }
    int e = i - off, j = e / C, c = e - j * C;
    float v;
    if (j < O) v = W[j * 2 * C + c];
    else { int jo = j - O; v = W[jo * 2 * C + C + c] - W[jo * 2 * C + c]; }
    wc[i] = v;
}

// ---------------------------------------------------------------- DIST GEMM (512-thread)
// FINAL form = r8 (proven 48us L4, VGPR 40, no spill). The cross-k0 prefetch
// pipeline was attempted three times (r2: launch-bounds VGPR cap; r10: lambda
// capture -> scratch; r12: macro/named-regs -> still scratch). All spilled:
// 4 live float4s across the fully-unrolled kk loop exceed what the allocator
// will keep resident. Plateau accepted: ~48us, VALUBusy ~35%, latency-bound
// at 2 blocks/CU.
template<bool VEC>
__launch_bounds__(512)
__global__ void k_dist(const float* __restrict__ A, int lda,
                       const float* __restrict__ xx,
                       float* __restrict__ C1, int Kd)
{
    constexpr int LDA_ = 132;              // 128 + 4 pad (k-major: [32 k][132])
    constexpr int LDT_ = 68;               // mirror T: [128 col][68]
    __shared__ float smem[8704];           // max(2*32*132=8448, 128*68=8704)
    float* As = smem;
    float* Bs = smem + 32 * LDA_;
    float* T  = smem;
    const int tid = threadIdx.x;
    const int tx  = tid & 31;              // 32 col groups x 4 cols = 128
    const int ty  = tid >> 5;              // 16 row groups

    int t = blockIdx.x;
    int it, jt;
    if (t < 120) {                          // off-diagonal pairs first
        int i = 0;
        for (; i < 15; ++i) { int cnt = 15 - i; if (t < cnt) break; t -= cnt; }
        it = i; jt = i + 1 + t;
    } else {                                // 16 diagonal tiles last (no mirror)
        it = jt = t - 120;
    }
    const int m0 = it * 128;
    const int n0 = jt * 128;
    const int b  = blockIdx.z;
    const float* Ab = A + (size_t)b * N_PTS * lda;

    float acc[2][4][4] = {};                // [ih(row half)][i(row)][c(col)]

    for (int k0 = 0; k0 < Kd; k0 += 32) {
        #pragma unroll
        for (int r = 0; r < 2; ++r) {
            int e = r * 512 + tid, row = e >> 3, kq = e & 7;
            if constexpr (VEC) {
                float4 v = *(const float4*)&Ab[(size_t)(m0 + row) * lda + k0 + kq * 4];
                As[(kq * 4 + 0) * LDA_ + row] = v.x;
                As[(kq * 4 + 1) * LDA_ + row] = v.y;
                As[(kq * 4 + 2) * LDA_ + row] = v.z;
                As[(kq * 4 + 3) * LDA_ + row] = v.w;
            } else {
                #pragma unroll
                for (int j = 0; j < 4; ++j) {
                    int kg = k0 + kq * 4 + j;
                    As[(kq * 4 + j) * LDA_ + row] =
                        (kg < Kd) ? Ab[(size_t)(m0 + row) * lda + kg] : 0.f;
                }
            }
        }
        #pragma unroll
        for (int r = 0; r < 2; ++r) {
            int e = r * 512 + tid, row = e >> 3, kq = e & 7;
            if constexpr (VEC) {
                float4 v = *(const float4*)&Ab[(size_t)(n0 + row) * lda + k0 + kq * 4];
                Bs[(kq * 4 + 0) * LDA_ + row] = v.x;
                Bs[(kq * 4 + 1) * LDA_ + row] = v.y;
                Bs[(kq * 4 + 2) * LDA_ + row] = v.z;
                Bs[(kq * 4 + 3) * LDA_ + row] = v.w;
            } else {
                #pragma unroll
                for (int j = 0; j < 4; ++j) {
                    int kg = k0 + kq * 4 + j;
                    Bs[(kq * 4 + j) * LDA_ + row] =
                        (kg < Kd) ? Ab[(size_t)(n0 + row) * lda + kg] : 0.f;
                }
            }
        }
        __syncthreads();

        if constexpr (VEC) {
            float4 ca0 = *(const float4*)&As[ty * 4];
            float4 ca1 = *(const float4*)&As[64 + ty * 4];
            float4 cb  = *(const float4*)&Bs[tx * 4];
            #pragma unroll
            for (int kk = 0; kk < 32; ++kk) {
                float4 na0, na1, nb;
                if (kk < 31) {
                    na0 = *(const float4*)&As[(kk + 1) * LDA_ + ty * 4];
                    na1 = *(const float4*)&As[(kk + 1) * LDA_ + 64 + ty * 4];
                    nb  = *(const float4*)&Bs[(kk + 1) * LDA_ + tx * 4];
                }
                float av[2][4] = {{ca0.x,ca0.y,ca0.z,ca0.w},{ca1.x,ca1.y,ca1.z,ca1.w}};
                float bw[4] = {cb.x, cb.y, cb.z, cb.w};
                #pragma unroll
                for (int ih = 0; ih < 2; ++ih)
                    #pragma unroll
                    for (int ii = 0; ii < 4; ++ii)
                        #pragma unroll
                        for (int jj = 0; jj < 4; ++jj)
                            acc[ih][ii][jj] = fmaf(av[ih][ii], bw[jj], acc[ih][ii][jj]);
                if (kk < 31) { ca0 = na0; ca1 = na1; cb = nb; }
            }
        } else {
            int klen = Kd - k0; if (klen > 32) klen = 32;
            #pragma unroll 8
            for (int kk = 0; kk < klen; ++kk) {
                float4 a0 = *(const float4*)&As[kk * LDA_ + ty * 4];
                float4 a1 = *(const float4*)&As[kk * LDA_ + 64 + ty * 4];
                float4 bq = *(const float4*)&Bs[kk * LDA_ + tx * 4];
                float av[2][4] = {{a0.x,a0.y,a0.z,a0.w},{a1.x,a1.y,a1.z,a1.w}};
                float bw[4] = {bq.x, bq.y, bq.z, bq.w};
                #pragma unroll
                for (int ih = 0; ih < 2; ++ih)
                    #pragma unroll
                    for (int ii = 0; ii < 4; ++ii)
                        #pragma unroll
                        for (int jj = 0; jj < 4; ++jj)
                            acc[ih][ii][jj] = fmaf(av[ih][ii], bw[jj], acc[ih][ii][jj]);
            }
        }
        __syncthreads();
    }

    const float* xxb = xx + b * N_PTS;
    float xj[4];
    {
        float4 v = *(const float4*)&xxb[n0 + tx * 4];
        xj[0] = v.x; xj[1] = v.y; xj[2] = v.z; xj[3] = v.w;
    }
    float xiv[2][4];
    #pragma unroll
    for (int ih = 0; ih < 2; ++ih)
        #pragma unroll
        for (int i = 0; i < 4; ++i)
            xiv[ih][i] = xxb[m0 + ih * 64 + ty * 4 + i];
    const bool diag = (m0 == n0);
    const size_t zoff = (size_t)b * N_PTS;

    #pragma unroll
    for (int ih = 0; ih < 2; ++ih)
        #pragma unroll
        for (int i = 0; i < 4; ++i) {
            int gi = m0 + ih * 64 + ty * 4 + i;
            float xi = xiv[ih][i];
            int gj = n0 + tx * 4;
            float4 v;
            v.x = 2.f * acc[ih][i][0] - xi - xj[0];
            v.y = 2.f * acc[ih][i][1] - xi - xj[1];
            v.z = 2.f * acc[ih][i][2] - xi - xj[2];
            v.w = 2.f * acc[ih][i][3] - xi - xj[3];
            if (diag) {
                if (gi == gj + 0) v.x = 0.f;
                if (gi == gj + 1) v.y = 0.f;
                if (gi == gj + 2) v.z = 0.f;
                if (gi == gj + 3) v.w = 0.f;
            }
            *(float4*)&C1[(zoff + gi) * N_PTS + gj] = v;
        }

    if (!diag) {                            // mirror: D2[j][i], LDS transpose
        #pragma unroll
        for (int ih = 0; ih < 2; ++ih) {
            #pragma unroll
            for (int c = 0; c < 4; ++c) {
                float xjc = xj[c];
                float4 tv;
                tv.x = 2.f * acc[ih][0][c] - xjc - xiv[ih][0];
                tv.y = 2.f * acc[ih][1][c] - xjc - xiv[ih][1];
                tv.z = 2.f * acc[ih][2][c] - xjc - xiv[ih][2];
                tv.w = 2.f * acc[ih][3][c] - xjc - xiv[ih][3];
                *(float4*)&T[(tx * 4 + c) * LDT_ + ty * 4] = tv;
            }
            __syncthreads();
            #pragma unroll
            for (int r = 0; r < 4; ++r) {
                int e = r * 512 + tid;
                int jr = e >> 4, c4 = e & 15;
                float4 tv = *(const float4*)&T[jr * LDT_ + c4 * 4];
                *(float4*)&C1[(zoff + n0 + jr) * N_PTS + m0 + ih * 64 + c4 * 4] = tv;
            }
            __syncthreads();
        }
    }
}

// ---------------------------------------------------------------- bf16 MFMA GEMM (layer 5)
__launch_bounds__(256)
__global__ void k_gemm5(const unsigned short* __restrict__ Ah,
                        const unsigned short* __restrict__ Bh,
                        float* __restrict__ Cf,
                        float* __restrict__ ssum, float* __restrict__ ssumsq)
{
    constexpr int LDA = 72;
    __shared__ unsigned short As[128 * LDA];
    __shared__ unsigned short Bs[128 * LDA];
    const int tid  = threadIdx.x;
    const int lane = tid & 63;
    const int w    = tid >> 6;
    const int wr   = w >> 1, wcl = w & 1;
    const int quad = lane >> 4;
    const int l16  = lane & 15;
    const int m0 = blockIdx.y * 128;
    const int n0 = blockIdx.x * 128;

    f32x4 acc[4][4] = {};

    for (int k0 = 0; k0 < 512; k0 += 64) {
        #pragma unroll
        for (int r = 0; r < 4; ++r) {
            int e = r * 256 + tid, row = e >> 3, kq = e & 7;
            *(uint4*)&As[row * LDA + kq * 8] =
                *(const uint4*)&Ah[(size_t)(m0 + row) * 512 + k0 + kq * 8];
        }
        #pragma unroll
        for (int r = 0; r < 4; ++r) {
            int e = r * 256 + tid, row = e >> 3, kq = e & 7;
            *(uint4*)&Bs[row * LDA + kq * 8] =
                *(const uint4*)&Bh[(size_t)(n0 + row) * 512 + k0 + kq * 8];
        }
        __syncthreads();
        #pragma unroll
        for (int kk = 0; kk < 64; kk += 32) {
            bf16x8 af[4], bfr[4];
            #pragma unroll
            for (int i = 0; i < 4; ++i)
                af[i] = *(const bf16x8*)&As[(wr * 64 + i * 16 + l16) * LDA + kk + quad * 8];
            #pragma unroll
            for (int j = 0; j < 4; ++j)
                bfr[j] = *(const bf16x8*)&Bs[(wcl * 64 + j * 16 + l16) * LDA + kk + quad * 8];
            #pragma unroll
            for (int i = 0; i < 4; ++i)
                #pragma unroll
                for (int j = 0; j < 4; ++j)
                    acc[i][j] = __builtin_amdgcn_mfma_f32_16x16x32_bf16(af[i], bfr[j], acc[i][j], 0, 0, 0);
        }
        __syncthreads();
    }

    #pragma unroll
    for (int i = 0; i < 4; ++i) {
        int rbase = m0 + wr * 64 + i * 16 + quad * 4;
        #pragma unroll
        for (int j = 0; j < 4; ++j) {
            int col = n0 + wcl * 64 + j * 16 + l16;
            #pragma unroll
            for (int r = 0; r < 4; ++r)
                Cf[(size_t)(rbase + r) * 1024 + col] = acc[i][j][r];
        }
    }

    float* sredS = (float*)As;
    float* sredQ = (float*)Bs;
    #pragma unroll
    for (int j = 0; j < 4; ++j) {
        float s = 0.f, q = 0.f;
        #pragma unroll
        for (int i = 0; i < 4; ++i)
            #pragma unroll
            for (int r = 0; r < 4; ++r) {
                float v = acc[i][j][r];
                s += v; q = fmaf(v, v, q);
            }
        int coll = wcl * 64 + j * 16 + l16;
        int slot = wr * 4 + quad;
        sredS[coll * 8 + slot] = s;
        sredQ[coll * 8 + slot] = q;
    }
    __syncthreads();
    if (tid < 128) {
        float s = 0.f, q = 0.f;
        #pragma unroll
        for (int t = 0; t < 8; ++t) { s += sredS[tid * 8 + t]; q += sredQ[tid * 8 + t]; }
        ssum  [blockIdx.y * 1024 + n0 + tid] = s;
        ssumsq[blockIdx.y * 1024 + n0 + tid] = q;
    }
}

// ---------------------------------------------------------------- FUSED select + GD GEMM
// GD part: unchanged (r6). Select: r9 form (lane-max 20th-largest lower bound
// at 1 ballot/iter + 4-candidate main bisection; exact full-count fallback).
template<bool VEC>
__launch_bounds__(256)
__global__ void k_selgd(const float* __restrict__ D2, int* __restrict__ idx_out,
                        const float* __restrict__ A, int lda,
                        const float* __restrict__ Bm, int ldb,
                        float* __restrict__ C1, float* __restrict__ C2,
                        int Nn, int Kd, int gdBlocks, int gdsh)
{
    constexpr int LDA_ = 132;
    constexpr int LDB_ = 68;
    __shared__ float smem[32 * LDA_ + 32 * LDB_];   // 25.6 KB (GD path only)

    if ((int)blockIdx.x < gdBlocks) {
        // ================= GD GEMM path =================
        float* As = smem;
        float* Bs = smem + 32 * LDA_;
        const int tid = threadIdx.x;
        const int tx  = tid & 15;
        const int ty  = tid >> 4;
        const int gdx = Nn >> 6;
        const int bx  = blockIdx.x & (gdx - 1);
        const int by  = blockIdx.x >> gdsh;
        const int m0 = by * 128;
        const int n0 = bx * 64;

        float acc[2][4][4] = {};

        for (int k0 = 0; k0 < Kd; k0 += 32) {
            #pragma unroll
            for (int r = 0; r < 4; ++r) {            // A: 128 rows x 32 k
                int e = r * 256 + tid, row = e >> 3, kq = e & 7;
                if constexpr (VEC) {
                    float4 v = *(const float4*)&A[(size_t)(m0 + row) * lda + k0 + kq * 4];
                    As[(kq * 4 + 0) * LDA_ + row] = v.x;
                    As[(kq * 4 + 1) * LDA_ + row] = v.y;
                    As[(kq * 4 + 2) * LDA_ + row] = v.z;
                    As[(kq * 4 + 3) * LDA_ + row] = v.w;
                } else {
                    #pragma unroll
                    for (int j = 0; j < 4; ++j) {
                        int kg = k0 + kq * 4 + j;
                        As[(kq * 4 + j) * LDA_ + row] =
                            (kg < Kd) ? A[(size_t)(m0 + row) * lda + kg] : 0.f;
                    }
                }
            }
            #pragma unroll
            for (int r = 0; r < 2; ++r) {            // B: 64 rows x 32 k
                int e = r * 256 + tid, row = e >> 3, kq = e & 7;
                if constexpr (VEC) {
                    float4 v = *(const float4*)&Bm[(size_t)(n0 + row) * ldb + k0 + kq * 4];
                    Bs[(kq * 4 + 0) * LDB_ + row] = v.x;
                    Bs[(kq * 4 + 1) * LDB_ + row] = v.y;
                    Bs[(kq * 4 + 2) * LDB_ + row] = v.z;
                    Bs[(kq * 4 + 3) * LDB_ + row] = v.w;
                } else {
                    #pragma unroll
                    for (int j = 0; j < 4; ++j) {
                        int kg = k0 + kq * 4 + j;
                        Bs[(kq * 4 + j) * LDB_ + row] =
                            (kg < Kd) ? Bm[(size_t)(n0 + row) * ldb + kg] : 0.f;
                    }
                }
            }
            __syncthreads();

            if constexpr (VEC) {
                float4 ca0 = *(const float4*)&As[ty * 4];
                float4 ca1 = *(const float4*)&As[64 + ty * 4];
                float4 cb0 = *(const float4*)&Bs[tx * 4];
                #pragma unroll
                for (int kk = 0; kk < 32; ++kk) {
                    float4 na0, na1, nb0;
                    if (kk < 31) {
                        na0 = *(const float4*)&As[(kk + 1) * LDA_ + ty * 4];
                        na1 = *(const float4*)&As[(kk + 1) * LDA_ + 64 + ty * 4];
                        nb0 = *(const float4*)&Bs[(kk + 1) * LDB_ + tx * 4];
                    }
                    float av[2][4] = {{ca0.x,ca0.y,ca0.z,ca0.w},{ca1.x,ca1.y,ca1.z,ca1.w}};
                    float bw[4] = {cb0.x, cb0.y, cb0.z, cb0.w};
                    #pragma unroll
                    for (int ih = 0; ih < 2; ++ih)
                        #pragma unroll
                        for (int ii = 0; ii < 4; ++ii)
                            #pragma unroll
                            for (int jj = 0; jj < 4; ++jj)
                                acc[ih][ii][jj] = fmaf(av[ih][ii], bw[jj], acc[ih][ii][jj]);
                    if (kk < 31) { ca0 = na0; ca1 = na1; cb0 = nb0; }
                }
            } else {
                int klen = Kd - k0; if (klen > 32) klen = 32;
                #pragma unroll 8
                for (int kk = 0; kk < klen; ++kk) {
                    float4 a0 = *(const float4*)&As[kk * LDA_ + ty * 4];
                    float4 a1 = *(const float4*)&As[kk * LDA_ + 64 + ty * 4];
                    float4 bq = *(const float4*)&Bs[kk * LDB_ + tx * 4];
                    float av[2][4] = {{a0.x,a0.y,a0.z,a0.w},{a1.x,a1.y,a1.z,a1.w}};
                    float bw[4] = {bq.x, bq.y, bq.z, bq.w};
                    #pragma unroll
                    for (int ih = 0; ih < 2; ++ih)
                        #pragma unroll
                        for (int ii = 0; ii < 4; ++ii)
                            #pragma unroll
                            for (int jj = 0; jj < 4; ++jj)
                                acc[ih][ii][jj] = fmaf(av[ih][ii], bw[jj], acc[ih][ii][jj]);
                }
            }
            __syncthreads();
        }

        const int Oo = Nn >> 1;
        #pragma unroll
        for (int ih = 0; ih < 2; ++ih)
            #pragma unroll
            for (int i = 0; i < 4; ++i) {
                int row = m0 + ih * 64 + ty * 4 + i;
                int colg = n0 + tx * 4;
                float4 v = make_float4(acc[ih][i][0], acc[ih][i][1],
                                       acc[ih][i][2], acc[ih][i][3]);
                if (colg < Oo) *(float4*)&C1[(size_t)row * Oo + colg] = v;
                else           *(float4*)&C2[(size_t)row * Oo + colg - Oo] = v;
            }
        return;
    }

    // ================= select path =================
    const int lane = threadIdx.x & 63;
    const int w    = threadIdx.x >> 6;
    const int qloc = ((int)blockIdx.x - gdBlocks) * 4 + w;   // 0..8191
    const float* row = D2 + (size_t)qloc * N_PTS;

    unsigned key[32];
    #pragma unroll
    for (int c = 0; c < 8; ++c) {
        float4 v = *(const float4*)&row[c * 256 + lane * 4];
        float vv[4] = {v.x, v.y, v.z, v.w};
        #pragma unroll
        for (int r = 0; r < 4; ++r) {
            unsigned u = __float_as_uint(vv[r]);
            key[c * 4 + r] = ((int)u >= 0) ? (u | 0x80000000u) : ~u;
        }
    }

    // per-lane max + wave min/max of lane maxes
    unsigned lmax = 0u;
    #pragma unroll
    for (int e = 0; e < 32; ++e) lmax = (key[e] > lmax) ? key[e] : lmax;
    unsigned gmin = lmax, gmax = lmax;
    #pragma unroll
    for (int s = 32; s >= 1; s >>= 1) {
        unsigned o1 = __shfl_xor(gmin, s, 64);
        unsigned o2 = __shfl_xor(gmax, s, 64);
        gmin = (o1 < gmin) ? o1 : gmin;
        gmax = (o2 > gmax) ? o2 : gmax;
    }

    // lo = exact 20th-largest lane-max via 1-ballot-per-iter bisection
    unsigned lo = gmin, hi2 = gmax;
    while (lo < hi2) {
        unsigned mid = lo + ((hi2 - lo) >> 1);
        int c = __popcll(__ballot(lmax > mid));
        if (c < KNN) hi2 = mid; else lo = mid + 1;
    }
    unsigned hi = gmax;

    // candidates >= lo (cap 4/lane; fake 0s never counted since mid >= lo > 0)
    unsigned c0 = 0u, c1 = 0u, c2 = 0u, c3 = 0u;
    int nc = 0;
    #pragma unroll
    for (int e = 0; e < 32; ++e) {
        unsigned k = key[e];
        if (k >= lo) {
            if (nc == 0) c0 = k; else if (nc == 1) c1 = k;
            else if (nc == 2) c2 = k; else if (nc == 3) c3 = k;
            ++nc;
        }
    }
    if (__ballot(nc > 4)) {
        // rare overflow: exact full-count bisection from current bounds
        while (lo < hi) {
            unsigned mid = lo + ((hi - lo) >> 1);
            int cnt = 0;
            #pragma unroll
            for (int e = 0; e < 32; ++e)
                cnt += __popcll(__ballot(key[e] > mid));
            if (cnt < KNN) hi = mid; else lo = mid + 1;
        }
    } else {
        // main bisection: 4 ballots/iter (cnt == count(key > mid) exactly)
        while (lo < hi) {
            unsigned mid = lo + ((hi - lo) >> 1);
            int cnt = __popcll(__ballot(c0 > mid))
                    + __popcll(__ballot(c1 > mid))
                    + __popcll(__ballot(c2 > mid))
                    + __popcll(__ballot(c3 > mid));
            if (cnt < KNN) hi = mid; else lo = mid + 1;
        }
    }
    const unsigned T = lo;

    int* outp = idx_out + (size_t)qloc * KNN;
    const unsigned long long ltmask = (lane == 0) ? 0ull : (~0ull >> (64 - lane));
    int base = 0;
    #pragma unroll
    for (int e = 0; e < 32; ++e) {
        bool p = key[e] > T;
        unsigned long long m = __ballot(p);
        if (p) {
            int pos = base + __popcll(m & ltmask);
            outp[pos] = (e >> 2) * 256 + lane * 4 + (e & 3);
        }
        base += __popcll(m);
    }
    // tie-fill: fully unrolled (no dynamic trip count!), writes guarded by pos<KNN
    #pragma unroll
    for (int e = 0; e < 32; ++e) {
        bool p = key[e] == T;
        unsigned long long m = __ballot(p);
        if (p) {
            int pos = base + __popcll(m & ltmask);
            if (pos < KNN) outp[pos] = (e >> 2) * 256 + lane * 4 + (e & 3);
        }
        base += __popcll(m);
    }
}

// ---------------------------------------------------------------- gather + stats
// sign(sc) == sign(gamma) (rsqrtf > 0), so max-vs-min selection is known up
// front; write ONE hsel array (r9).
template<int O, int NSEQ>
__launch_bounds__(256)
__global__ void k_gather(const float* __restrict__ gtab, const float* __restrict__ dtab,
                         const int* __restrict__ idx, const float* __restrict__ gamma,
                         float* __restrict__ hsel,
                         float* __restrict__ ssum, float* __restrict__ ssumsq)
{
    constexpr int NPB = 256 / O;
    const int grp = threadIdx.x / O;
    const int o   = threadIdx.x & (O - 1);
    const float g = gamma[o];
    float accS = 0.f, accS2 = 0.f;
    const int rowsPerBlock = NPB * NSEQ;
    const int batch = blockIdx.x & 3;
    const int chunk = blockIdx.x >> 2;
    const int bbase = batch << 11;
    for (int s = 0; s < NSEQ; ++s) {
        int row = bbase + chunk * rowsPerBlock + s * NPB + grp;
        const int* ip = idx + (size_t)row * KNN;
        float gmax = -INFINITY, gmin = INFINITY, gs = 0.f, gs2 = 0.f;
        for (int k = 0; k < KNN; ++k) {
            int nb = ip[k];
            float v = gtab[(size_t)(bbase + nb) * O + o];
            gmax = fmaxf(gmax, v);
            gmin = fminf(gmin, v);
            gs  += v;
            gs2  = fmaf(v, v, gs2);
        }
        float d = dtab[(size_t)row * O + o];
        float keep = (g >= 0.f) ? gmax : gmin;
        hsel[(size_t)row * O + o] = keep + d;
        accS  += gs + (float)KNN * d;
        accS2 += gs2 + 2.f * d * gs + (float)KNN * d * d;
    }
    int bank = blockIdx.x & 63;
    atomicAdd(&ssum[bank * O + o], accS);
    atomicAdd(&ssumsq[bank * O + o], accS2);
}

// ---------------------------------------------------------------- normalize (+BN finalize, +xx, +bf16 mirror)
template<int O, bool WRITE_XX>
__launch_bounds__(256)
__global__ void k_normalize(const float* __restrict__ hsel,
                            const float* __restrict__ ssum, const float* __restrict__ ssumsq,
                            const float* __restrict__ gamma, const float* __restrict__ beta,
                            float invM, float* __restrict__ xcs,
                            __hip_bfloat16* __restrict__ xch, float* __restrict__ xx)
{
    const int tid = threadIdx.x;
    const int o   = tid & (O - 1);
    float s = 0.f, s2 = 0.f;
    #pragma unroll 8
    for (int bk = 0; bk < 64; ++bk) { s += ssum[bk * O + o]; s2 += ssumsq[bk * O + o]; }
    float mean = s * invM;
    float var  = fmaf(-mean, mean, s2 * invM);
    float sc   = gamma[o] * rsqrtf(var + EPSV);
    float sh   = beta[o] - mean * sc;

    constexpr int R = 256 / O;
    const int rloc = tid / O;
    __shared__ float part[4];
    const int ngroups = BN_ROWS / R;
    for (int gidx = blockIdx.x; gidx < ngroups; gidx += gridDim.x) {
        int row = gidx * R + rloc;
        size_t i = (size_t)row * O + o;
        float h = hsel[i];                      // pre-selected by sign(gamma)
        float y = fmaf(h, sc, sh);
        y = (y >= 0.f) ? y : SLOPEV * y;
        xcs[(size_t)row * 512 + o] = y;
        xch[(size_t)row * 512 + o] = __float2bfloat16(y);
        if constexpr (WRITE_XX) {
            float p = y * y;
            #pragma unroll
            for (int sft = 32; sft >= 1; sft >>= 1) p += __shfl_xor(p, sft, 64);
            if constexpr (O == 64) {
                if ((tid & 63) == 0) xx[row] = p;
            } else {
                if ((tid & 63) == 0) part[tid >> 6] = p;
                __syncthreads();
                if constexpr (O == 128) {
                    if (tid < 2) xx[gidx * R + tid] = part[2 * tid] + part[2 * tid + 1];
                } else {
                    if (tid == 0) xx[gidx * R] = (part[0] + part[1]) + (part[2] + part[3]);
                }
                __syncthreads();
            }
        }
    }
}

// ---------------------------------------------------------------- seg max/sum (+finalize, 64 banks)
__global__ void k_seg(const float* __restrict__ h,
                      const float* __restrict__ ssum, const float* __restrict__ ssumsq,
                      const float* __restrict__ gamma, const float* __restrict__ beta,
                      float* __restrict__ smax, float* __restrict__ ssumseg)
{
    int f = blockIdx.y * 256 + threadIdx.x;
    float s = 0.f, s2 = 0.f;
    #pragma unroll 8
    for (int bk = 0; bk < 64; ++bk) { s += ssum[bk * 1024 + f]; s2 += ssumsq[bk * 1024 + f]; }
    const float invM = 1.f / (float)BN_ROWS;
    float mean = s * invM;
    float var  = fmaf(-mean, mean, s2 * invM);
    float sc   = gamma[f] * rsqrtf(var + EPSV);
    float sh   = beta[f] - mean * sc;

    int seg = blockIdx.x;
    float mx = -INFINITY, sm = 0.f;
    int n0 = seg * 64;
    for (int i = 0; i < 64; ++i) {
        float v = fmaf(h[(size_t)(n0 + i) * 1024 + f], sc, sh);
        v = (v >= 0.f) ? v : SLOPEV * v;
        mx = fmaxf(mx, v); sm += v;
    }
    smax[(size_t)seg * 1024 + f]    = mx;
    ssumseg[(size_t)seg * 1024 + f] = sm;
}

// ---------------------------------------------------------------- final projection (+bin combine)
__launch_bounds__(256)
__global__ void k_final(const float* __restrict__ smax, const float* __restrict__ ssg,
                        const float* __restrict__ Wft, const float* __restrict__ bfeat,
                        float* __restrict__ out)
{
    __shared__ float row[1024];
    __shared__ float part[1024];
    const int tid = threadIdx.x;
    int sb = blockIdx.x;             // s*4 + b, s in 0..62
    int s = sb >> 2, b = sb & 3;
    int nb = (s == 0) ? 1 : (s < 3) ? 2 : (s < 7) ? 4 : (s < 15) ? 8 : (s < 31) ? 16 : 32;
    int idxL = s - (nb - 1);
    int segc = 32 / nb;
    int seg0 = b * 32 + idxL * segc;
    float inv = 1.f / (float)(64 * segc);
    for (int c = tid; c < 1024; c += 256) {
        float mx = -INFINITY, sm = 0.f;
        for (int t = 0; t < segc; ++t) {
            mx = fmaxf(mx, smax[(size_t)(seg0 + t) * 1024 + c]);
            sm += ssg[(size_t)(seg0 + t) * 1024 + c];
        }
        row[c] = mx + sm * inv;
    }
    __syncthreads();

    const int lane = tid & 63;
    const int w    = tid >> 6;
    const float* rw = row + w * 256;
    const float* wp = Wft + (size_t)(w * 256) * 256 + lane * 4;
    float4 a0 = {0,0,0,0}, a1 = {0,0,0,0}, a2 = {0,0,0,0}, a3 = {0,0,0,0};
    for (int f = 0; f < 256; f += 4) {
        float r0 = rw[f + 0], r1 = rw[f + 1], r2 = rw[f + 2], r3 = rw[f + 3];
        float4 w0 = *(const float4*)&wp[(size_t)(f + 0) * 256];
        float4 w1 = *(const float4*)&wp[(size_t)(f + 1) * 256];
        float4 w2 = *(const float4*)&wp[(size_t)(f + 2) * 256];
        float4 w3 = *(const float4*)&wp[(size_t)(f + 3) * 256];
        a0.x = fmaf(r0, w0.x, a0.x); a0.y = fmaf(r0, w0.y, a0.y);
        a0.z = fmaf(r0, w0.z, a0.z); a0.w = fmaf(r0, w0.w, a0.w);
        a1.x = fmaf(r1, w1.x, a1.x); a1.y = fmaf(r1, w1.y, a1.y);
        a1.z = fmaf(r1, w1.z, a1.z); a1.w = fmaf(r1, w1.w, a1.w);
        a2.x = fmaf(r2, w2.x, a2.x); a2.y = fmaf(r2, w2.y, a2.y);
        a2.z = fmaf(r2, w2.z, a2.z); a2.w = fmaf(r2, w2.w, a2.w);
        a3.x = fmaf(r3, w3.x, a3.x); a3.y = fmaf(r3, w3.y, a3.y);
        a3.z = fmaf(r3, w3.z, a3.z); a3.w = fmaf(r3, w3.w, a3.w);
    }
    float4 a;
    a.x = (a0.x + a1.x) + (a2.x + a3.x);
    a.y = (a0.y + a1.y) + (a2.y + a3.y);
    a.z = (a0.z + a1.z) + (a2.z + a3.z);
    a.w = (a0.w + a1.w) + (a2.w + a3.w);
    *(float4*)&part[w * 256 + lane * 4] = a;
    __syncthreads();
    int o = tid;
    float acc = (part[o] + part[256 + o]) + (part[512 + o] + part[768 + o]);
    out[(size_t)sb * 256 + o] = acc + bfeat[o];
}

// ================================================================ launch
extern "C" void kernel_launch(void* const* d_in, const int* in_sizes, int n_in,
                              void* d_out, int out_size, void* d_ws, size_t ws_size,
                              hipStream_t stream)
{
    const float* x  = (const float*)d_in[0];
    const float* W1 = (const float*)d_in[1];
    const float* g1 = (const float*)d_in[2];
    const float* b1 = (const float*)d_in[3];
    const float* W2 = (const float*)d_in[4];
    const float* g2 = (const float*)d_in[5];
    const float* b2 = (const float*)d_in[6];
    const float* W3 = (const float*)d_in[7];
    const float* g3 = (const float*)d_in[8];
    const float* b3 = (const float*)d_in[9];
    const float* W4 = (const float*)d_in[10];
    const float* g4 = (const float*)d_in[11];
    const float* b4 = (const float*)d_in[12];
    const float* W5 = (const float*)d_in[13];
    const float* g5 = (const float*)d_in[14];
    const float* b5 = (const float*)d_in[15];
    const float* Wf = (const float*)d_in[16];
    const float* bfeat = (const float*)d_in[17];
    float* out = (float*)d_out;
    float* ws  = (float*)d_ws;

    // workspace layout (floats), total 32,727,552 = 130.9 MB (ws_size ~268 MB)
    float* xt1   = ws + 0;            // 24576
    int*   idx   = (int*)(ws + 24576);// 163840
    float* xx    = ws + 188416;       // 8192
    float* xc    = ws + 196608;       // 8192*512
    float* hsel  = ws + 4390912;      // 8192*256
    float* stats = ws + 8585216;      // 65536 (L1@0 L2@8192 L3@16384 L4@32768)
    float* smax  = ws + 8650752;      // 128*1024
    float* ssg   = ws + 8781824;      // 128*1024
    float* wc    = ws + 8912896;      // 90624
    float* big   = ws + 9003520;      // 16,777,216 (4-batch D2 | h5)
    __hip_bfloat16* xch = (__hip_bfloat16*)(ws + 25780736);  // 8192*512 bf16
    __hip_bfloat16* w5h = (__hip_bfloat16*)(ws + 27877888);  // 1024*512 bf16
    float* wft   = ws + 28140032;     // 1024*256 transposed Wf
    float* l5s   = ws + 28402176;     // 64*1024 L5 col sums
    float* l5q   = ws + 28467712;     // 64*1024 L5 col sumsq
    float* gtab  = ws + 28533248;     // 8192*256 (outside big: selgd overlap)
    float* dtab  = ws + 30630400;     // 8192*256  (end: 32,727,552)

    hipMemsetAsync(stats, 0, 65536 * sizeof(float), stream);
    k_transpose<<<32, 256, 0, stream>>>(x, xt1, xx);
    k_prepw_all<<<3426, 256, 0, stream>>>(W1, W2, W3, W4, W5, Wf, wc, w5h, wft);

    const float invMk = 1.f / (float)(BN_ROWS * KNN);

    // ------------- layer 1: C=3, O=64
    {
        float* ss = stats + 0;
        k_dist<false><<<dim3(136, 1, 4), 512, 0, stream>>>(xt1, 3, xx, big, 3);
        k_selgd<false><<<128 + 2048, 256, 0, stream>>>(big, idx, xt1, 3, wc, 3, gtab, dtab, 128, 3, 128, 1);
        k_gather<64, 8><<<256, 256, 0, stream>>>(gtab, dtab, idx, g1, hsel, ss, ss + 4096);
        k_normalize<64, true><<<512, 256, 0, stream>>>(hsel, ss, ss + 4096, g1, b1, invMk, xc + 0, xch + 0, xx);
    }
    // ------------- layer 2: C=64, O=64
    {
        float* ss = stats + 8192;
        k_dist<true><<<dim3(136, 1, 4), 512, 0, stream>>>(xc + 0, 512, xx, big, 64);
        k_selgd<true><<<128 + 2048, 256, 0, stream>>>(big, idx, xc + 0, 512, wc + 384, 64, gtab, dtab, 128, 64, 128, 1);
        k_gather<64, 8><<<256, 256, 0, stream>>>(gtab, dtab, idx, g2, hsel, ss, ss + 4096);
        k_normalize<64, true><<<512, 256, 0, stream>>>(hsel, ss, ss + 4096, g2, b2, invMk, xc + 64, xch + 64, xx);
    }
    // ------------- layer 3: C=64, O=128
    {
        float* ss = stats + 16384;
        k_dist<true><<<dim3(136, 1, 4), 512, 0, stream>>>(xc + 64, 512, xx, big, 64);
        k_selgd<true><<<256 + 2048, 256, 0, stream>>>(big, idx, xc + 64, 512, wc + 8576, 64, gtab, dtab, 256, 64, 256, 2);
        k_gather<128, 8><<<512, 256, 0, stream>>>(gtab, dtab, idx, g3, hsel, ss, ss + 8192);
        k_normalize<128, true><<<512, 256, 0, stream>>>(hsel, ss, ss + 8192, g3, b3, invMk, xc + 128, xch + 128, xx);
    }
    // ------------- layer 4: C=128, O=256
    {
        float* ss = stats + 32768;
        k_dist<true><<<dim3(136, 1, 4), 512, 0, stream>>>(xc + 128, 512, xx, big, 128);
        k_selgd<true><<<512 + 2048, 256, 0, stream>>>(big, idx, xc + 128, 512, wc + 24960, 128, gtab, dtab, 512, 128, 512, 3);
        k_gather<256, 8><<<1024, 256, 0, stream>>>(gtab, dtab, idx, g4, hsel, ss, ss + 16384);
        k_normalize<256, false><<<512, 256, 0, stream>>>(hsel, ss, ss + 16384, g4, b4, invMk, xc + 256, xch + 256, xx);
    }
    // ------------- layer 5: bf16 MFMA GEMM (+fused stats), seg, final
    {
        k_gemm5<<<dim3(8, 64), 256, 0, stream>>>((const unsigned short*)xch, (const unsigned short*)w5h, big, l5s, l5q);
        k_seg<<<dim3(128, 4), 256, 0, stream>>>(big, l5s, l5q, g5, b5, smax, ssg);
        k_final<<<252, 256, 0, stream>>>(smax, ssg, wft, bfeat, out);
    }
}